// Round 21
// baseline (367.679 us; speedup 1.0000x reference)
//
#include <hip/hip_runtime.h>
#include <hip/hip_bf16.h>
#include <math.h>

// ---------------------------------------------------------------------------
// AASIST-like net. N = B*S = 4*1024 = 4096 graph nodes.
// Attention trick: e_ij = leaky_relu(s1_i + s2_j + ab).  Sorting j by s2 makes
// the lr branch a threshold; softmax@h becomes prefix/suffix scans (exact).
// Conv: 4 oc/wave, 2-wave channel-split, each wave runs TWO interleaved
// channel streams (independent load chains) for latency hiding.
// ---------------------------------------------------------------------------

#define NN 4096          // graph nodes
#define BB 4             // batch

// ---------------- conv_time: Conv1d(1,128,3,p=1)+BN+ReLU, padded output -----
__global__ void k_conv_time3(const float* __restrict__ x, const float* __restrict__ w,
                             const float* __restrict__ cb, const float* __restrict__ g,
                             const float* __restrict__ bbp, const float* __restrict__ m,
                             const float* __restrict__ v, float* __restrict__ out) {
  int gid = blockIdx.x * 256 + threadIdx.x;     // 4*128*1024
  int t4 = gid & 1023;
  int o = (gid >> 10) & 127;
  int b = gid >> 17;
  int t = t4 * 4;
  float sc = g[o] * rsqrtf(v[o] + 1e-5f);
  float sh = (cb[o] - m[o]) * sc + bbp[o];
  const float* xb = x + b * 4096;
  float4 xc = *(const float4*)&xb[t];
  float xm = (t > 0) ? xb[t - 1] : 0.f;
  float xp = (t + 4 < 4096) ? xb[t + 4] : 0.f;
  const float* wo = w + o * 3;
  float w0 = wo[0], w1 = wo[1], w2 = wo[2];
  float4 y;
  y.x = fmaxf((w0 * xm   + w1 * xc.x + w2 * xc.y) * sc + sh, 0.f);
  y.y = fmaxf((w0 * xc.x + w1 * xc.y + w2 * xc.z) * sc + sh, 0.f);
  y.z = fmaxf((w0 * xc.y + w1 * xc.z + w2 * xc.w) * sc + sh, 0.f);
  y.w = fmaxf((w0 * xc.z + w1 * xc.w + w2 * xp  ) * sc + sh, 0.f);
  float* orow = out + ((size_t)(b * 128) + o) * 4104 + 4;
  *(float4*)&orow[t] = y;
  if (t4 == 0)    { orow[-4] = 0.f; orow[-3] = 0.f; orow[-2] = 0.f; orow[-1] = 0.f; }
  if (t4 == 1023) { orow[4096] = 0.f; orow[4097] = 0.f; orow[4098] = 0.f; orow[4099] = 0.f; }
}

// ---- Conv1d(C,O,3,p=1)+BN+ReLU+MaxPool2: 2-wave split, 2 streams/wave ------
// Wave wv covers channels [wv*C/2,(wv+1)*C/2), processed as two interleaved
// streams (cc and cc+QC, QC=C/4) with independent load chains into shared acc.
template <int C, int TIN, int OPAD>
__global__ __launch_bounds__(128, 8)
void k_conv_pair2(const float* __restrict__ in, const float* __restrict__ w,
                  const float* __restrict__ cb, const float* __restrict__ g,
                  const float* __restrict__ bbp, const float* __restrict__ m,
                  const float* __restrict__ v, float* __restrict__ out, int OCH) {
  constexpr int TOUT = TIN / 2;
  constexpr int IST = TIN + 8;
  constexpr int HC = C / 2;
  constexpr int QC = HC / 2;
  const int OST = TOUT + 2 * OPAD;
  __shared__ float red[16 * 64];    // wave1 partials: [oi*4+p][lane]

  int nT = TIN / 256;
  int bx = blockIdx.x;
  int tb = bx % nT;
  int oq = (bx / nT) % (OCH / 4);
  int b  = bx / (nT * (OCH / 4));
  int tid = threadIdx.x;
  int lane = tid & 63;
  int wv = __builtin_amdgcn_readfirstlane(tid >> 6);
  int t0 = tb * 256;

  float acc[4][4];
  #pragma unroll
  for (int oi = 0; oi < 4; oi++)
    #pragma unroll
    for (int p = 0; p < 4; p++) acc[oi][p] = 0.f;

  const float* wq = w + (size_t)(oq * 4) * C * 3 + (size_t)(wv * HC) * 3;  // uniform
  const float* xb0 = in + ((size_t)(b * C) + wv * HC) * IST + 4 + t0 + 4 * lane;
  const float* xb1 = xb0 + (size_t)QC * IST;

  float4 A0 = *(const float4*)(xb0 - 1);
  float2 B0 = *(const float2*)(xb0 + 3);
  float4 A1 = *(const float4*)(xb1 - 1);
  float2 B1 = *(const float2*)(xb1 + 3);
  for (int cc = 0; cc < QC; ++cc) {
    float4 An0, An1; float2 Bn0, Bn1;
    if (cc + 1 < QC) {
      const float* n0 = xb0 + (size_t)(cc + 1) * IST;
      const float* n1 = xb1 + (size_t)(cc + 1) * IST;
      An0 = *(const float4*)(n0 - 1);
      Bn0 = *(const float2*)(n0 + 3);
      An1 = *(const float4*)(n1 - 1);
      Bn1 = *(const float2*)(n1 + 3);
    }
    const float* wr0 = wq + (size_t)cc * 3;
    const float* wr1 = wq + (size_t)(QC + cc) * 3;
    #pragma unroll
    for (int oi = 0; oi < 4; oi++) {
      const float* wo0 = wr0 + (size_t)oi * C * 3;           // uniform -> s_load
      float u0 = wo0[0], u1 = wo0[1], u2 = wo0[2];
      acc[oi][0] += u0 * A0.x + u1 * A0.y + u2 * A0.z;
      acc[oi][1] += u0 * A0.y + u1 * A0.z + u2 * A0.w;
      acc[oi][2] += u0 * A0.z + u1 * A0.w + u2 * B0.x;
      acc[oi][3] += u0 * A0.w + u1 * B0.x + u2 * B0.y;
      const float* wo1 = wr1 + (size_t)oi * C * 3;           // uniform -> s_load
      float q0 = wo1[0], q1 = wo1[1], q2 = wo1[2];
      acc[oi][0] += q0 * A1.x + q1 * A1.y + q2 * A1.z;
      acc[oi][1] += q0 * A1.y + q1 * A1.z + q2 * A1.w;
      acc[oi][2] += q0 * A1.z + q1 * A1.w + q2 * B1.x;
      acc[oi][3] += q0 * A1.w + q1 * B1.x + q2 * B1.y;
    }
    A0 = An0; B0 = Bn0; A1 = An1; B1 = Bn1;
  }

  if (wv == 1) {
    #pragma unroll
    for (int oi = 0; oi < 4; oi++)
      #pragma unroll
      for (int p = 0; p < 4; p++)
        red[(oi * 4 + p) * 64 + lane] = acc[oi][p];
  }
  __syncthreads();
  if (wv == 0) {
    int base_o = oq * 4;
    #pragma unroll
    for (int oi = 0; oi < 4; oi++) {
      int o = base_o + oi;
      float sc = g[o] * rsqrtf(v[o] + 1e-5f);
      float sh = (cb[o] - m[o]) * sc + bbp[o];
      float y0 = acc[oi][0] + red[(oi * 4 + 0) * 64 + lane];
      float y1 = acc[oi][1] + red[(oi * 4 + 1) * 64 + lane];
      float y2 = acc[oi][2] + red[(oi * 4 + 2) * 64 + lane];
      float y3 = acc[oi][3] + red[(oi * 4 + 3) * 64 + lane];
      float2 r;
      r.x = fmaxf(fmaxf(y0 * sc + sh, y1 * sc + sh), 0.f);
      r.y = fmaxf(fmaxf(y2 * sc + sh, y3 * sc + sh), 0.f);
      *(float2*)&out[((size_t)(b * OCH) + o) * OST + OPAD + tb * 128 + 2 * lane] = r;
    }
    if (OPAD > 0 && tb == 0) {
      if (lane < 4) {
        float* row = out + ((size_t)(b * OCH) + base_o + lane) * OST;
        row[0] = 0.f; row[1] = 0.f; row[2] = 0.f; row[3] = 0.f;
      } else if (lane < 8) {
        float* row = out + ((size_t)(b * OCH) + base_o + lane - 4) * OST;
        row[OPAD + TOUT + 0] = 0.f; row[OPAD + TOUT + 1] = 0.f;
        row[OPAD + TOUT + 2] = 0.f; row[OPAD + TOUT + 3] = 0.f;
      }
    }
  }
}

// ------------- GAT1 GEMM: A CHW [4][512][1024], Wt [512][512], 128x64 tile --
__global__ __launch_bounds__(512, 4)
void k_gemm_chw(const float* __restrict__ A, const float* __restrict__ Wt,
                const float* __restrict__ bias, float* __restrict__ Cout) {
  constexpr int K = 512, N = 512;
  __shared__ float As[32][132];
  __shared__ float Bs[32][68];
  int i0 = blockIdx.x * 128, j0 = blockIdx.y * 64;
  int tid = threadIdx.x;
  int tx = tid & 15, ty = tid >> 4;
  int b = i0 >> 10, s0 = i0 & 1023;
  const float* Ab = A + (size_t)b * K * 1024 + s0;

  float acc[4][4];
  #pragma unroll
  for (int ii = 0; ii < 4; ii++)
    #pragma unroll
    for (int jj = 0; jj < 4; jj++) acc[ii][jj] = 0.f;

  int ka = (tid + 0) >> 5, i4a = tid & 31;
  int kb = (tid + 512) >> 5, i4b = tid & 31;
  float4 pa0, pa1; float pb[4];

  pa0 = *(const float4*)&Ab[(size_t)ka * 1024 + 4 * i4a];
  pa1 = *(const float4*)&Ab[(size_t)kb * 1024 + 4 * i4b];
  #pragma unroll
  for (int r = 0; r < 4; r++) {
    int e = tid + 512 * r; int j = e >> 5, k = e & 31;
    pb[r] = Wt[(size_t)(j0 + j) * K + k];
  }

  for (int kt = 0; kt < K; kt += 32) {
    *(float4*)&As[ka][4 * i4a] = pa0;
    *(float4*)&As[kb][4 * i4b] = pa1;
    #pragma unroll
    for (int r = 0; r < 4; r++) {
      int e = tid + 512 * r; int j = e >> 5, k = e & 31;
      Bs[k][j] = pb[r];
    }
    __syncthreads();
    int ktn = (kt + 32 < K) ? kt + 32 : 0;
    float4 na0 = *(const float4*)&Ab[(size_t)(ktn + ka) * 1024 + 4 * i4a];
    float4 na1 = *(const float4*)&Ab[(size_t)(ktn + kb) * 1024 + 4 * i4b];
    float nb[4];
    #pragma unroll
    for (int r = 0; r < 4; r++) {
      int e = tid + 512 * r; int j = e >> 5, k = e & 31;
      nb[r] = Wt[(size_t)(j0 + j) * K + ktn + k];
    }
    #pragma unroll 4
    for (int kk = 0; kk < 32; ++kk) {
      float4 a4 = *(const float4*)&As[kk][ty * 4];
      float4 b4 = *(const float4*)&Bs[kk][tx * 4];
      float a[4] = {a4.x, a4.y, a4.z, a4.w};
      float bv[4] = {b4.x, b4.y, b4.z, b4.w};
      #pragma unroll
      for (int ii = 0; ii < 4; ii++)
        #pragma unroll
        for (int jj = 0; jj < 4; jj++) acc[ii][jj] += a[ii] * bv[jj];
    }
    __syncthreads();
    pa0 = na0; pa1 = na1;
    #pragma unroll
    for (int r = 0; r < 4; r++) pb[r] = nb[r];
  }

  float4 bias4 = *(const float4*)&bias[j0 + 4 * tx];
  #pragma unroll
  for (int ii = 0; ii < 4; ii++) {
    int i = i0 + ty * 4 + ii;
    float4 o4;
    o4.x = acc[ii][0] + bias4.x; o4.y = acc[ii][1] + bias4.y;
    o4.z = acc[ii][2] + bias4.z; o4.w = acc[ii][3] + bias4.w;
    *(float4*)&Cout[(size_t)i * N + j0 + 4 * tx] = o4;
  }
}

// ------------- GAT2 GEMM: A row-major [4096][512], 64x64 tile ---------------
__global__ __launch_bounds__(256, 4)
void k_gemm_rm(const float* __restrict__ A, const float* __restrict__ Wt,
               const float* __restrict__ bias, float* __restrict__ Cout) {
  constexpr int K = 512, N = 256;
  __shared__ float As[32][68];
  __shared__ float Bs[32][68];
  int i0 = blockIdx.x * 64, j0 = blockIdx.y * 64;
  int tid = threadIdx.x;
  int tx = tid & 15, ty = tid >> 4;

  float acc[4][4];
  #pragma unroll
  for (int ii = 0; ii < 4; ii++)
    #pragma unroll
    for (int jj = 0; jj < 4; jj++) acc[ii][jj] = 0.f;

  float4 pa[2]; float pb[8];
  #pragma unroll
  for (int r = 0; r < 2; r++) {
    int e4 = tid + 256 * r; int i = e4 >> 3, k4 = e4 & 7;
    pa[r] = *(const float4*)&A[(size_t)(i0 + i) * K + 4 * k4];
  }
  #pragma unroll
  for (int r = 0; r < 8; r++) {
    int e = tid + 256 * r; int j = e >> 5, k = e & 31;
    pb[r] = Wt[(size_t)(j0 + j) * K + k];
  }

  for (int kt = 0; kt < K; kt += 32) {
    #pragma unroll
    for (int r = 0; r < 2; r++) {
      int e4 = tid + 256 * r; int i = e4 >> 3, k4 = e4 & 7;
      As[4 * k4 + 0][i] = pa[r].x; As[4 * k4 + 1][i] = pa[r].y;
      As[4 * k4 + 2][i] = pa[r].z; As[4 * k4 + 3][i] = pa[r].w;
    }
    #pragma unroll
    for (int r = 0; r < 8; r++) {
      int e = tid + 256 * r; int j = e >> 5, k = e & 31;
      Bs[k][j] = pb[r];
    }
    __syncthreads();
    int ktn = (kt + 32 < K) ? kt + 32 : 0;
    float4 na[2]; float nb[8];
    #pragma unroll
    for (int r = 0; r < 2; r++) {
      int e4 = tid + 256 * r; int i = e4 >> 3, k4 = e4 & 7;
      na[r] = *(const float4*)&A[(size_t)(i0 + i) * K + ktn + 4 * k4];
    }
    #pragma unroll
    for (int r = 0; r < 8; r++) {
      int e = tid + 256 * r; int j = e >> 5, k = e & 31;
      nb[r] = Wt[(size_t)(j0 + j) * K + ktn + k];
    }
    #pragma unroll 4
    for (int kk = 0; kk < 32; ++kk) {
      float4 a4 = *(const float4*)&As[kk][ty * 4];
      float4 b4 = *(const float4*)&Bs[kk][tx * 4];
      float a[4] = {a4.x, a4.y, a4.z, a4.w};
      float bv[4] = {b4.x, b4.y, b4.z, b4.w};
      #pragma unroll
      for (int ii = 0; ii < 4; ii++)
        #pragma unroll
        for (int jj = 0; jj < 4; jj++) acc[ii][jj] += a[ii] * bv[jj];
    }
    __syncthreads();
    pa[0] = na[0]; pa[1] = na[1];
    #pragma unroll
    for (int r = 0; r < 8; r++) pb[r] = nb[r];
  }

  float4 bias4 = *(const float4*)&bias[j0 + 4 * tx];
  #pragma unroll
  for (int ii = 0; ii < 4; ii++) {
    int i = i0 + ty * 4 + ii;
    float4 o4;
    o4.x = acc[ii][0] + bias4.x; o4.y = acc[ii][1] + bias4.y;
    o4.z = acc[ii][2] + bias4.z; o4.w = acc[ii][3] + bias4.w;
    *(float4*)&Cout[(size_t)i * N + j0 + 4 * tx] = o4;
  }
}

// ---------------- s1/s2 row dots: s1=h·aw[:D], s2=h·aw[D:] ------------------
template <int D>
__global__ void k_rowdot(const float* __restrict__ h, const float* __restrict__ aw,
                         float* __restrict__ s1, float* __restrict__ s2,
                         int* __restrict__ rnk) {
  if (blockIdx.x < 16) rnk[blockIdx.x * 256 + threadIdx.x] = 0;
  int wid = threadIdx.x >> 6, lane = threadIdx.x & 63;
  int i = blockIdx.x * 4 + wid;
  const float* hr = h + (size_t)i * D;
  float d1 = 0.f, d2 = 0.f;
  #pragma unroll
  for (int d = lane; d < D; d += 64) {
    float hv = hr[d];
    d1 += hv * aw[d];
    d2 += hv * aw[D + d];
  }
  for (int off = 32; off; off >>= 1) {
    d1 += __shfl_down(d1, off, 64);
    d2 += __shfl_down(d2, off, 64);
  }
  if (lane == 0) { s1[i] = d1; s2[i] = d2; }
}

// ---------------- rank by counting ------------------------------------------
__global__ void k_rank(const float* __restrict__ s2v, int* __restrict__ rnk) {
  __shared__ float ls[1024];
  int j = blockIdx.x * 256 + threadIdx.x;
  int base = blockIdx.y * 1024;
  float vj = s2v[j];
  for (int e = threadIdx.x; e < 1024; e += 256) ls[e] = s2v[base + e];
  __syncthreads();
  int cnt = 0;
  #pragma unroll 8
  for (int r = 0; r < 1024; ++r) {
    float vr = ls[r];
    cnt += (vr < vj || (vr == vj && (base + r) < j)) ? 1 : 0;
  }
  atomicAdd(&rnk[j], cnt);
}

__global__ void k_scatter(const float* __restrict__ s2v, const int* __restrict__ rnk,
                          float* __restrict__ svals, int* __restrict__ sidx) {
  int j = blockIdx.x * 256 + threadIdx.x;
  int r = rnk[j];
  svals[r] = s2v[j];
  sidx[r] = j;
}

// ------------- chunk column sums + (block 128) denominator scans ------------
template <int D>
__global__ void k_chunksum(const float* __restrict__ h, const int* __restrict__ sidx,
                           const float* __restrict__ svals,
                           float* __restrict__ csP, float* __restrict__ csM,
                           float* __restrict__ preden, float* __restrict__ sufden) {
  constexpr int CPT = D / 256;
  int c = blockIdx.x, tid = threadIdx.x;
  __shared__ float shr[512];         // reused: [csP256|csM256] for block 128
  if (c == 128) {
    // denominator scans (former k_scan_den)
    float* csPd = shr;
    float* csMd = shr + 256;
    int base = tid * 16;
    float M2 = svals[NN - 1];
    float lwp[16], lwm[16];
    #pragma unroll
    for (int u = 0; u < 16; u++) {
      float d = svals[base + u] - M2;
      lwp[u] = expf(d);
      lwm[u] = expf(0.01f * d);
    }
    float smm = 0.f, spp = 0.f;
    #pragma unroll
    for (int u = 0; u < 16; u++) { smm += lwm[u]; spp += lwp[u]; }
    csMd[tid] = smm; csPd[tid] = spp;
    __syncthreads();
    float offM = 0.f;
    for (int cc = 0; cc < tid; cc++) offM += csMd[cc];
    float offP = 0.f;
    for (int cc = tid + 1; cc < 256; cc++) offP += csPd[cc];
    float run = offM;
    #pragma unroll
    for (int u = 0; u < 16; u++) { preden[base + u] = run; run += lwm[u]; }
    if (tid == 255) preden[NN] = run;
    float runp = offP;
    if (tid == 255) sufden[NN] = 0.f;
    #pragma unroll
    for (int u = 15; u >= 0; u--) { runp += lwp[u]; sufden[base + u] = runp; }
    return;
  }
  __shared__ int lidx[32];
  __shared__ float lwp2[32], lwm2[32];
  if (tid < 32) {
    int r = c * 32 + tid;
    float d = svals[r] - svals[NN - 1];
    lidx[tid] = sidx[r]; lwp2[tid] = expf(d); lwm2[tid] = expf(0.01f * d);
  }
  __syncthreads();
  float aP[CPT], aM[CPT];
  #pragma unroll
  for (int q = 0; q < CPT; q++) { aP[q] = 0.f; aM[q] = 0.f; }
  for (int u = 0; u < 32; u++) {
    const float* hr = h + (size_t)lidx[u] * D;
    float fp = lwp2[u], fm = lwm2[u];
    #pragma unroll
    for (int q = 0; q < CPT; q++) {
      float hv = hr[tid + q * 256];
      aP[q] += fp * hv; aM[q] += fm * hv;
    }
  }
  #pragma unroll
  for (int q = 0; q < CPT; q++) {
    csP[(size_t)c * D + tid + q * 256] = aP[q];
    csM[(size_t)c * D + tid + q * 256] = aM[q];
  }
}

// ------------- chunk offsets, batched loads, 128-thr blocks -----------------
template <int D>
__global__ void k_chunkoff(const float* __restrict__ csP, const float* __restrict__ csM,
                           float* __restrict__ offP, float* __restrict__ offM) {
  int d = blockIdx.x * 128 + threadIdx.x;
  float rm = 0.f;
  for (int cb = 0; cb < 128; cb += 16) {
    float vals[16];
    #pragma unroll
    for (int u = 0; u < 16; u++) vals[u] = csM[(size_t)(cb + u) * D + d];
    #pragma unroll
    for (int u = 0; u < 16; u++) { offM[(size_t)(cb + u) * D + d] = rm; rm += vals[u]; }
  }
  float rp = 0.f;
  for (int cb = 127; cb >= 15; cb -= 16) {
    float vals[16];
    #pragma unroll
    for (int u = 0; u < 16; u++) vals[u] = csP[(size_t)(cb - u) * D + d];
    #pragma unroll
    for (int u = 0; u < 16; u++) { offP[(size_t)(cb - u) * D + d] = rp; rp += vals[u]; }
  }
}

// ------------- write full prefix (Pre) and suffix (Suf) arrays --------------
template <int D>
__global__ void k_scanwrite(const float* __restrict__ h, const int* __restrict__ sidx,
                            const float* __restrict__ svals,
                            const float* __restrict__ offP, const float* __restrict__ offM,
                            float* __restrict__ Pre, float* __restrict__ Suf) {
  constexpr int CPT = D / 256;
  int c = blockIdx.x, tid = threadIdx.x;
  __shared__ int lidx[32];
  __shared__ float lwp[32], lwm[32];
  if (tid < 32) {
    int r = c * 32 + tid;
    float d = svals[r] - svals[NN - 1];
    lidx[tid] = sidx[r]; lwp[tid] = expf(d); lwm[tid] = expf(0.01f * d);
  }
  __syncthreads();
  float runM[CPT], runP[CPT];
  #pragma unroll
  for (int q = 0; q < CPT; q++) {
    int d = tid + q * 256;
    runM[q] = offM[(size_t)c * D + d];
    runP[q] = offP[(size_t)c * D + d];
  }
  for (int u = 0; u < 32; u++) {
    const float* hr = h + (size_t)lidx[u] * D;
    float fm = lwm[u];
    #pragma unroll
    for (int q = 0; q < CPT; q++) {
      int d = tid + q * 256;
      Pre[(size_t)(c * 32 + u) * D + d] = runM[q];
      runM[q] += fm * hr[d];
    }
  }
  if (c == 127) {
    #pragma unroll
    for (int q = 0; q < CPT; q++) Pre[(size_t)NN * D + tid + q * 256] = runM[q];
    #pragma unroll
    for (int q = 0; q < CPT; q++) Suf[(size_t)NN * D + tid + q * 256] = 0.f;
  }
  for (int u = 31; u >= 0; u--) {
    const float* hr = h + (size_t)lidx[u] * D;
    float fp = lwp[u];
    #pragma unroll
    for (int q = 0; q < CPT; q++) {
      int d = tid + q * 256;
      runP[q] += fp * hr[d];
      Suf[(size_t)(c * 32 + u) * D + d] = runP[q];
    }
  }
}

// ------------- apply (threshold/A/B computed inline) ------------------------
template <int D>
__global__ void k_apply(const float* __restrict__ Pre, const float* __restrict__ Suf,
                        const float* __restrict__ preden, const float* __restrict__ sufden,
                        const float* __restrict__ s1, const float* __restrict__ svals,
                        const float* __restrict__ abp, float* __restrict__ outg) {
  int i = blockIdx.x;
  float ab = abp[0], M2 = svals[NN - 1];
  float alpha = s1[i] + ab;
  float cthr = -alpha;
  int lo = 0, hi = NN;
  while (lo < hi) {
    int mid = (lo + hi) >> 1;
    if (svals[mid] < cthr) lo = mid + 1; else hi = mid;
  }
  int t = lo;
  float e1 = alpha + M2;
  float gam = fmaxf(e1, 0.01f * e1);
  float A = expf(e1 - gam);
  float Bv = expf(0.01f * e1 - gam);
  float den = A * sufden[t] + Bv * preden[t];
  float inv = 1.f / den;
  const float* Pr = Pre + (size_t)t * D;
  const float* Sr = Suf + (size_t)t * D;
  for (int d = threadIdx.x; d < D; d += 256)
    outg[(size_t)i * D + d] = (A * Sr[d] + Bv * Pr[d]) * inv;
}

// ------------- mean-pool over S (2-stage) + final Linear(256,2) -------------
__global__ void k_pool(const float* __restrict__ g2, float* __restrict__ pp) {
  int b = blockIdx.x >> 4, ch = blockIdx.x & 15;
  const float* base = g2 + ((size_t)(b * 1024) + ch * 64) * 256 + threadIdx.x;
  float s = 0.f;
  for (int r = 0; r < 64; r++) s += base[(size_t)r * 256];
  pp[(size_t)blockIdx.x * 256 + threadIdx.x] = s;
}

__global__ void k_head2(const float* __restrict__ pp, const float* __restrict__ fcw,
                        const float* __restrict__ fcb, float* __restrict__ out) {
  __shared__ float pooled[4][256];
  int tid = threadIdx.x;
  for (int b = 0; b < 4; b++) {
    float s = 0.f;
    for (int ch = 0; ch < 16; ch++) s += pp[(size_t)(b * 16 + ch) * 256 + tid];
    pooled[b][tid] = s * (1.f / 1024.f);
  }
  __syncthreads();
  if (tid < 8) {
    int b = tid >> 1, c = tid & 1;
    float acc = fcb[c];
    for (int cc = 0; cc < 256; cc++) acc += pooled[b][cc] * fcw[c * 256 + cc];
    out[b * 2 + c] = acc;
  }
}

// ---------------------------------------------------------------------------
extern "C" void kernel_launch(void* const* d_in, const int* in_sizes, int n_in,
                              void* d_out, int out_size, void* d_ws, size_t ws_size,
                              hipStream_t stream) {
  const float* x    = (const float*)d_in[0];
  const float* ctw  = (const float*)d_in[1];
  const float* ctb  = (const float*)d_in[2];
  const float* bn0g = (const float*)d_in[3];
  const float* bn0b = (const float*)d_in[4];
  const float* bn0m = (const float*)d_in[5];
  const float* bn0v = (const float*)d_in[6];
  const float* c1w  = (const float*)d_in[7];
  const float* c1b  = (const float*)d_in[8];
  const float* bn1g = (const float*)d_in[9];
  const float* bn1b = (const float*)d_in[10];
  const float* bn1m = (const float*)d_in[11];
  const float* bn1v = (const float*)d_in[12];
  const float* c2w  = (const float*)d_in[13];
  const float* c2b  = (const float*)d_in[14];
  const float* bn2g = (const float*)d_in[15];
  const float* bn2b = (const float*)d_in[16];
  const float* bn2m = (const float*)d_in[17];
  const float* bn2v = (const float*)d_in[18];
  const float* g1w  = (const float*)d_in[19];
  const float* g1b  = (const float*)d_in[20];
  const float* g1aw = (const float*)d_in[21];
  const float* g1ab = (const float*)d_in[22];
  const float* g2w  = (const float*)d_in[23];
  const float* g2b  = (const float*)d_in[24];
  const float* g2aw = (const float*)d_in[25];
  const float* g2ab = (const float*)d_in[26];
  const float* fcw  = (const float*)d_in[27];
  const float* fcb  = (const float*)d_in[28];
  float* ws = (float*)d_ws;

  const size_t S0SZ = (size_t)4 * 128 * 4104;   // padded conv_time out
  const size_t S1SZ = (size_t)4 * 256 * 2056;   // padded conv1 out
  const size_t SLOT = (size_t)(NN + 1) * 512;
  float* slot0 = ws;                      // conv_time out -> Suf
  float* slot1 = ws + S0SZ;               // conv1 out -> Pre
  float* slot2 = slot1 + S1SZ;            // conv2 out -> g1 -> g2
  float* slot3 = slot2 + SLOT;            // h1 -> h2
  float* sm    = slot3 + SLOT;            // smalls
  float* s1    = sm;                      // 4096
  float* s2    = sm + 4096;
  float* svals = sm + 8192;
  int*   sidx  = (int*)(sm + 12288);
  float* preden = sm + 16384;             // 4097
  float* sufden = sm + 20488;             // 4097
  float* csP   = sm + 24592;              // 128*512
  float* csM   = csP + 65536;
  float* offP  = csM + 65536;
  float* offM  = offP + 65536;
  int*   rnk   = (int*)(offM + 65536);    // 4096
  float* pp    = offM + 65536 + 4096;     // 16384

  // ---- convs ----
  k_conv_time3<<<BB * 128 * 1024 / 256, 256, 0, stream>>>(x, ctw, ctb, bn0g, bn0b, bn0m, bn0v, slot0);
  k_conv_pair2<128, 4096, 4><<<BB * 64 * 16, 128, 0, stream>>>(
      slot0, c1w, c1b, bn1g, bn1b, bn1m, bn1v, slot1, 256);
  k_conv_pair2<256, 2048, 0><<<BB * 128 * 8, 128, 0, stream>>>(
      slot1, c2w, c2b, bn2g, bn2b, bn2m, bn2v, slot2, 512);

  // ---- GAT1 ----
  k_gemm_chw<<<dim3(32, 8), 512, 0, stream>>>(slot2, g1w, g1b, slot3);
  k_rowdot<512><<<NN / 4, 256, 0, stream>>>(slot3, g1aw, s1, s2, rnk);
  k_rank<<<dim3(16, 4), 256, 0, stream>>>(s2, rnk);
  k_scatter<<<16, 256, 0, stream>>>(s2, rnk, svals, sidx);
  k_chunksum<512><<<129, 256, 0, stream>>>(slot3, sidx, svals, csP, csM, preden, sufden);
  k_chunkoff<512><<<4, 128, 0, stream>>>(csP, csM, offP, offM);
  k_scanwrite<512><<<128, 256, 0, stream>>>(slot3, sidx, svals, offP, offM, slot1, slot0);
  k_apply<512><<<NN, 256, 0, stream>>>(slot1, slot0, preden, sufden, s1, svals, g1ab, slot2);

  // ---- GAT2 ----
  k_gemm_rm<<<dim3(64, 4), 256, 0, stream>>>(slot2, g2w, g2b, slot3);
  k_rowdot<256><<<NN / 4, 256, 0, stream>>>(slot3, g2aw, s1, s2, rnk);
  k_rank<<<dim3(16, 4), 256, 0, stream>>>(s2, rnk);
  k_scatter<<<16, 256, 0, stream>>>(s2, rnk, svals, sidx);
  k_chunksum<256><<<129, 256, 0, stream>>>(slot3, sidx, svals, csP, csM, preden, sufden);
  k_chunkoff<256><<<2, 128, 0, stream>>>(csP, csM, offP, offM);
  k_scanwrite<256><<<128, 256, 0, stream>>>(slot3, sidx, svals, offP, offM, slot1, slot0);
  k_apply<256><<<NN, 256, 0, stream>>>(slot1, slot0, preden, sufden, s1, svals, g2ab, slot2);

  // ---- head ----
  k_pool<<<BB * 16, 256, 0, stream>>>(slot2, pp);
  k_head2<<<1, 256, 0, stream>>>(pp, fcw, fcb, (float*)d_out);
}

// Round 22
// 365.353 us; speedup vs baseline: 1.0064x; 1.0064x over previous
//
#include <hip/hip_runtime.h>
#include <hip/hip_bf16.h>
#include <math.h>

// ---------------------------------------------------------------------------
// AASIST-like net. N = B*S = 4*1024 = 4096 graph nodes.
// Attention trick: e_ij = leaky_relu(s1_i + s2_j + ab).  Sorting j by s2 makes
// the lr branch a threshold; softmax@h becomes prefix/suffix scans (exact).
// Conv: R14/R17 config (4 oc/wave, 2-wave channel-split, LDS reduce).
// GAT chain: k_tw folded into apply/scan_den/chunksum/scanwrite.
// Best measured configuration: 365.4 / 366.2 us.
// ---------------------------------------------------------------------------

#define NN 4096          // graph nodes
#define BB 4             // batch

// ---------------- conv_time: Conv1d(1,128,3,p=1)+BN+ReLU, padded output -----
__global__ void k_conv_time3(const float* __restrict__ x, const float* __restrict__ w,
                             const float* __restrict__ cb, const float* __restrict__ g,
                             const float* __restrict__ bbp, const float* __restrict__ m,
                             const float* __restrict__ v, float* __restrict__ out) {
  int gid = blockIdx.x * 256 + threadIdx.x;     // 4*128*1024
  int t4 = gid & 1023;
  int o = (gid >> 10) & 127;
  int b = gid >> 17;
  int t = t4 * 4;
  float sc = g[o] * rsqrtf(v[o] + 1e-5f);
  float sh = (cb[o] - m[o]) * sc + bbp[o];
  const float* xb = x + b * 4096;
  float4 xc = *(const float4*)&xb[t];
  float xm = (t > 0) ? xb[t - 1] : 0.f;
  float xp = (t + 4 < 4096) ? xb[t + 4] : 0.f;
  const float* wo = w + o * 3;
  float w0 = wo[0], w1 = wo[1], w2 = wo[2];
  float4 y;
  y.x = fmaxf((w0 * xm   + w1 * xc.x + w2 * xc.y) * sc + sh, 0.f);
  y.y = fmaxf((w0 * xc.x + w1 * xc.y + w2 * xc.z) * sc + sh, 0.f);
  y.z = fmaxf((w0 * xc.y + w1 * xc.z + w2 * xc.w) * sc + sh, 0.f);
  y.w = fmaxf((w0 * xc.z + w1 * xc.w + w2 * xp  ) * sc + sh, 0.f);
  float* orow = out + ((size_t)(b * 128) + o) * 4104 + 4;
  *(float4*)&orow[t] = y;
  if (t4 == 0)    { orow[-4] = 0.f; orow[-3] = 0.f; orow[-2] = 0.f; orow[-1] = 0.f; }
  if (t4 == 1023) { orow[4096] = 0.f; orow[4097] = 0.f; orow[4098] = 0.f; orow[4099] = 0.f; }
}

// ---- Conv1d(C,O,3,p=1)+BN+ReLU+MaxPool2: 4 oc/wave, 2-wave channel-split ---
// (Best measured conv: 103 us each, ~60% occupancy, VGPR 24, 0 conflicts.)
template <int C, int TIN, int OPAD>
__global__ __launch_bounds__(128, 8)
void k_conv_pair(const float* __restrict__ in, const float* __restrict__ w,
                 const float* __restrict__ cb, const float* __restrict__ g,
                 const float* __restrict__ bbp, const float* __restrict__ m,
                 const float* __restrict__ v, float* __restrict__ out, int OCH) {
  constexpr int TOUT = TIN / 2;
  constexpr int IST = TIN + 8;
  constexpr int HC = C / 2;
  const int OST = TOUT + 2 * OPAD;
  __shared__ float red[16 * 64];    // wave1 partials: [oi*4+p][lane]

  int nT = TIN / 256;
  int bx = blockIdx.x;
  int tb = bx % nT;
  int oq = (bx / nT) % (OCH / 4);
  int b  = bx / (nT * (OCH / 4));
  int tid = threadIdx.x;
  int lane = tid & 63;
  int wv = __builtin_amdgcn_readfirstlane(tid >> 6);
  int t0 = tb * 256;

  float acc[4][4];
  #pragma unroll
  for (int oi = 0; oi < 4; oi++)
    #pragma unroll
    for (int p = 0; p < 4; p++) acc[oi][p] = 0.f;

  const float* wq = w + (size_t)(oq * 4) * C * 3 + (size_t)(wv * HC) * 3;  // uniform
  const float* xb = in + ((size_t)(b * C) + wv * HC) * IST + 4 + t0 + 4 * lane;

  float4 A = *(const float4*)(xb - 1);
  float2 Bv = *(const float2*)(xb + 3);
  for (int cc = 0; cc < HC; ++cc) {
    float4 An; float2 Bn;
    if (cc + 1 < HC) {
      const float* nx = xb + (size_t)(cc + 1) * IST;
      An = *(const float4*)(nx - 1);
      Bn = *(const float2*)(nx + 3);
    }
    const float* wr = wq + (size_t)cc * 3;
    #pragma unroll
    for (int oi = 0; oi < 4; oi++) {
      const float* wo = wr + (size_t)oi * C * 3;             // uniform -> s_load
      float w0 = wo[0], w1 = wo[1], w2 = wo[2];
      acc[oi][0] += w0 * A.x + w1 * A.y + w2 * A.z;
      acc[oi][1] += w0 * A.y + w1 * A.z + w2 * A.w;
      acc[oi][2] += w0 * A.z + w1 * A.w + w2 * Bv.x;
      acc[oi][3] += w0 * A.w + w1 * Bv.x + w2 * Bv.y;
    }
    A = An; Bv = Bn;
  }

  if (wv == 1) {
    #pragma unroll
    for (int oi = 0; oi < 4; oi++)
      #pragma unroll
      for (int p = 0; p < 4; p++)
        red[(oi * 4 + p) * 64 + lane] = acc[oi][p];
  }
  __syncthreads();
  if (wv == 0) {
    int base_o = oq * 4;
    #pragma unroll
    for (int oi = 0; oi < 4; oi++) {
      int o = base_o + oi;
      float sc = g[o] * rsqrtf(v[o] + 1e-5f);
      float sh = (cb[o] - m[o]) * sc + bbp[o];
      float y0 = acc[oi][0] + red[(oi * 4 + 0) * 64 + lane];
      float y1 = acc[oi][1] + red[(oi * 4 + 1) * 64 + lane];
      float y2 = acc[oi][2] + red[(oi * 4 + 2) * 64 + lane];
      float y3 = acc[oi][3] + red[(oi * 4 + 3) * 64 + lane];
      float2 r;
      r.x = fmaxf(fmaxf(y0 * sc + sh, y1 * sc + sh), 0.f);
      r.y = fmaxf(fmaxf(y2 * sc + sh, y3 * sc + sh), 0.f);
      *(float2*)&out[((size_t)(b * OCH) + o) * OST + OPAD + tb * 128 + 2 * lane] = r;
    }
    if (OPAD > 0 && tb == 0) {
      if (lane < 4) {
        float* row = out + ((size_t)(b * OCH) + base_o + lane) * OST;
        row[0] = 0.f; row[1] = 0.f; row[2] = 0.f; row[3] = 0.f;
      } else if (lane < 8) {
        float* row = out + ((size_t)(b * OCH) + base_o + lane - 4) * OST;
        row[OPAD + TOUT + 0] = 0.f; row[OPAD + TOUT + 1] = 0.f;
        row[OPAD + TOUT + 2] = 0.f; row[OPAD + TOUT + 3] = 0.f;
      }
    }
  }
}

// ------------- GAT1 GEMM: A CHW [4][512][1024], Wt [512][512], 128x64 tile --
__global__ __launch_bounds__(512, 4)
void k_gemm_chw(const float* __restrict__ A, const float* __restrict__ Wt,
                const float* __restrict__ bias, float* __restrict__ Cout) {
  constexpr int K = 512, N = 512;
  __shared__ float As[32][132];
  __shared__ float Bs[32][68];
  int i0 = blockIdx.x * 128, j0 = blockIdx.y * 64;
  int tid = threadIdx.x;
  int tx = tid & 15, ty = tid >> 4;
  int b = i0 >> 10, s0 = i0 & 1023;
  const float* Ab = A + (size_t)b * K * 1024 + s0;

  float acc[4][4];
  #pragma unroll
  for (int ii = 0; ii < 4; ii++)
    #pragma unroll
    for (int jj = 0; jj < 4; jj++) acc[ii][jj] = 0.f;

  int ka = (tid + 0) >> 5, i4a = tid & 31;
  int kb = (tid + 512) >> 5, i4b = tid & 31;
  float4 pa0, pa1; float pb[4];

  pa0 = *(const float4*)&Ab[(size_t)ka * 1024 + 4 * i4a];
  pa1 = *(const float4*)&Ab[(size_t)kb * 1024 + 4 * i4b];
  #pragma unroll
  for (int r = 0; r < 4; r++) {
    int e = tid + 512 * r; int j = e >> 5, k = e & 31;
    pb[r] = Wt[(size_t)(j0 + j) * K + k];
  }

  for (int kt = 0; kt < K; kt += 32) {
    *(float4*)&As[ka][4 * i4a] = pa0;
    *(float4*)&As[kb][4 * i4b] = pa1;
    #pragma unroll
    for (int r = 0; r < 4; r++) {
      int e = tid + 512 * r; int j = e >> 5, k = e & 31;
      Bs[k][j] = pb[r];
    }
    __syncthreads();
    int ktn = (kt + 32 < K) ? kt + 32 : 0;
    float4 na0 = *(const float4*)&Ab[(size_t)(ktn + ka) * 1024 + 4 * i4a];
    float4 na1 = *(const float4*)&Ab[(size_t)(ktn + kb) * 1024 + 4 * i4b];
    float nb[4];
    #pragma unroll
    for (int r = 0; r < 4; r++) {
      int e = tid + 512 * r; int j = e >> 5, k = e & 31;
      nb[r] = Wt[(size_t)(j0 + j) * K + ktn + k];
    }
    #pragma unroll 4
    for (int kk = 0; kk < 32; ++kk) {
      float4 a4 = *(const float4*)&As[kk][ty * 4];
      float4 b4 = *(const float4*)&Bs[kk][tx * 4];
      float a[4] = {a4.x, a4.y, a4.z, a4.w};
      float bv[4] = {b4.x, b4.y, b4.z, b4.w};
      #pragma unroll
      for (int ii = 0; ii < 4; ii++)
        #pragma unroll
        for (int jj = 0; jj < 4; jj++) acc[ii][jj] += a[ii] * bv[jj];
    }
    __syncthreads();
    pa0 = na0; pa1 = na1;
    #pragma unroll
    for (int r = 0; r < 4; r++) pb[r] = nb[r];
  }

  float4 bias4 = *(const float4*)&bias[j0 + 4 * tx];
  #pragma unroll
  for (int ii = 0; ii < 4; ii++) {
    int i = i0 + ty * 4 + ii;
    float4 o4;
    o4.x = acc[ii][0] + bias4.x; o4.y = acc[ii][1] + bias4.y;
    o4.z = acc[ii][2] + bias4.z; o4.w = acc[ii][3] + bias4.w;
    *(float4*)&Cout[(size_t)i * N + j0 + 4 * tx] = o4;
  }
}

// ------------- GAT2 GEMM: A row-major [4096][512], 64x64 tile ---------------
__global__ __launch_bounds__(256, 4)
void k_gemm_rm(const float* __restrict__ A, const float* __restrict__ Wt,
               const float* __restrict__ bias, float* __restrict__ Cout) {
  constexpr int K = 512, N = 256;
  __shared__ float As[32][68];
  __shared__ float Bs[32][68];
  int i0 = blockIdx.x * 64, j0 = blockIdx.y * 64;
  int tid = threadIdx.x;
  int tx = tid & 15, ty = tid >> 4;

  float acc[4][4];
  #pragma unroll
  for (int ii = 0; ii < 4; ii++)
    #pragma unroll
    for (int jj = 0; jj < 4; jj++) acc[ii][jj] = 0.f;

  float4 pa[2]; float pb[8];
  #pragma unroll
  for (int r = 0; r < 2; r++) {
    int e4 = tid + 256 * r; int i = e4 >> 3, k4 = e4 & 7;
    pa[r] = *(const float4*)&A[(size_t)(i0 + i) * K + 4 * k4];
  }
  #pragma unroll
  for (int r = 0; r < 8; r++) {
    int e = tid + 256 * r; int j = e >> 5, k = e & 31;
    pb[r] = Wt[(size_t)(j0 + j) * K + k];
  }

  for (int kt = 0; kt < K; kt += 32) {
    #pragma unroll
    for (int r = 0; r < 2; r++) {
      int e4 = tid + 256 * r; int i = e4 >> 3, k4 = e4 & 7;
      As[4 * k4 + 0][i] = pa[r].x; As[4 * k4 + 1][i] = pa[r].y;
      As[4 * k4 + 2][i] = pa[r].z; As[4 * k4 + 3][i] = pa[r].w;
    }
    #pragma unroll
    for (int r = 0; r < 8; r++) {
      int e = tid + 256 * r; int j = e >> 5, k = e & 31;
      Bs[k][j] = pb[r];
    }
    __syncthreads();
    int ktn = (kt + 32 < K) ? kt + 32 : 0;
    float4 na[2]; float nb[8];
    #pragma unroll
    for (int r = 0; r < 2; r++) {
      int e4 = tid + 256 * r; int i = e4 >> 3, k4 = e4 & 7;
      na[r] = *(const float4*)&A[(size_t)(i0 + i) * K + ktn + 4 * k4];
    }
    #pragma unroll
    for (int r = 0; r < 8; r++) {
      int e = tid + 256 * r; int j = e >> 5, k = e & 31;
      nb[r] = Wt[(size_t)(j0 + j) * K + ktn + k];
    }
    #pragma unroll 4
    for (int kk = 0; kk < 32; ++kk) {
      float4 a4 = *(const float4*)&As[kk][ty * 4];
      float4 b4 = *(const float4*)&Bs[kk][tx * 4];
      float a[4] = {a4.x, a4.y, a4.z, a4.w};
      float bv[4] = {b4.x, b4.y, b4.z, b4.w};
      #pragma unroll
      for (int ii = 0; ii < 4; ii++)
        #pragma unroll
        for (int jj = 0; jj < 4; jj++) acc[ii][jj] += a[ii] * bv[jj];
    }
    __syncthreads();
    pa[0] = na[0]; pa[1] = na[1];
    #pragma unroll
    for (int r = 0; r < 8; r++) pb[r] = nb[r];
  }

  float4 bias4 = *(const float4*)&bias[j0 + 4 * tx];
  #pragma unroll
  for (int ii = 0; ii < 4; ii++) {
    int i = i0 + ty * 4 + ii;
    float4 o4;
    o4.x = acc[ii][0] + bias4.x; o4.y = acc[ii][1] + bias4.y;
    o4.z = acc[ii][2] + bias4.z; o4.w = acc[ii][3] + bias4.w;
    *(float4*)&Cout[(size_t)i * N + j0 + 4 * tx] = o4;
  }
}

// ---------------- s1/s2 row dots: s1=h·aw[:D], s2=h·aw[D:] ------------------
template <int D>
__global__ void k_rowdot(const float* __restrict__ h, const float* __restrict__ aw,
                         float* __restrict__ s1, float* __restrict__ s2,
                         int* __restrict__ rnk) {
  if (blockIdx.x < 16) rnk[blockIdx.x * 256 + threadIdx.x] = 0;
  int wid = threadIdx.x >> 6, lane = threadIdx.x & 63;
  int i = blockIdx.x * 4 + wid;
  const float* hr = h + (size_t)i * D;
  float d1 = 0.f, d2 = 0.f;
  #pragma unroll
  for (int d = lane; d < D; d += 64) {
    float hv = hr[d];
    d1 += hv * aw[d];
    d2 += hv * aw[D + d];
  }
  for (int off = 32; off; off >>= 1) {
    d1 += __shfl_down(d1, off, 64);
    d2 += __shfl_down(d2, off, 64);
  }
  if (lane == 0) { s1[i] = d1; s2[i] = d2; }
}

// ---------------- rank by counting ------------------------------------------
__global__ void k_rank(const float* __restrict__ s2v, int* __restrict__ rnk) {
  __shared__ float ls[1024];
  int j = blockIdx.x * 256 + threadIdx.x;
  int base = blockIdx.y * 1024;
  float vj = s2v[j];
  for (int e = threadIdx.x; e < 1024; e += 256) ls[e] = s2v[base + e];
  __syncthreads();
  int cnt = 0;
  #pragma unroll 8
  for (int r = 0; r < 1024; ++r) {
    float vr = ls[r];
    cnt += (vr < vj || (vr == vj && (base + r) < j)) ? 1 : 0;
  }
  atomicAdd(&rnk[j], cnt);
}

__global__ void k_scatter(const float* __restrict__ s2v, const int* __restrict__ rnk,
                          float* __restrict__ svals, int* __restrict__ sidx) {
  int j = blockIdx.x * 256 + threadIdx.x;
  int r = rnk[j];
  svals[r] = s2v[j];
  sidx[r] = j;
}

// ------------- scalar denominator scans (one block, exps inline) ------------
__global__ void k_scan_den(const float* __restrict__ svals,
                           float* __restrict__ preden, float* __restrict__ sufden) {
  __shared__ float csP[256], csM[256];
  int tid = threadIdx.x;
  int base = tid * 16;
  float M2 = svals[NN - 1];
  float lwp[16], lwm[16];
  #pragma unroll
  for (int u = 0; u < 16; u++) {
    float d = svals[base + u] - M2;
    lwp[u] = expf(d);
    lwm[u] = expf(0.01f * d);
  }
  float sm = 0.f, sp = 0.f;
  #pragma unroll
  for (int u = 0; u < 16; u++) { sm += lwm[u]; sp += lwp[u]; }
  csM[tid] = sm; csP[tid] = sp;
  __syncthreads();
  float offM = 0.f;
  for (int c = 0; c < tid; c++) offM += csM[c];
  float offP = 0.f;
  for (int c = tid + 1; c < 256; c++) offP += csP[c];
  float run = offM;
  #pragma unroll
  for (int u = 0; u < 16; u++) { preden[base + u] = run; run += lwm[u]; }
  if (tid == 255) preden[NN] = run;
  float runp = offP;
  if (tid == 255) sufden[NN] = 0.f;
  #pragma unroll
  for (int u = 15; u >= 0; u--) { runp += lwp[u]; sufden[base + u] = runp; }
}

// ------------- chunk column sums (128 chunks of 32 sorted rows) -------------
template <int D>
__global__ void k_chunksum(const float* __restrict__ h, const int* __restrict__ sidx,
                           const float* __restrict__ svals,
                           float* __restrict__ csP, float* __restrict__ csM) {
  constexpr int CPT = D / 256;
  int c = blockIdx.x, tid = threadIdx.x;
  __shared__ int lidx[32];
  __shared__ float lwp[32], lwm[32];
  if (tid < 32) {
    int r = c * 32 + tid;
    float d = svals[r] - svals[NN - 1];
    lidx[tid] = sidx[r]; lwp[tid] = expf(d); lwm[tid] = expf(0.01f * d);
  }
  __syncthreads();
  float aP[CPT], aM[CPT];
  #pragma unroll
  for (int q = 0; q < CPT; q++) { aP[q] = 0.f; aM[q] = 0.f; }
  for (int u = 0; u < 32; u++) {
    const float* hr = h + (size_t)lidx[u] * D;
    float fp = lwp[u], fm = lwm[u];
    #pragma unroll
    for (int q = 0; q < CPT; q++) {
      float hv = hr[tid + q * 256];
      aP[q] += fp * hv; aM[q] += fm * hv;
    }
  }
  #pragma unroll
  for (int q = 0; q < CPT; q++) {
    csP[(size_t)c * D + tid + q * 256] = aP[q];
    csM[(size_t)c * D + tid + q * 256] = aM[q];
  }
}

// ------------- chunk offsets, batched loads, 128-thr blocks -----------------
template <int D>
__global__ void k_chunkoff(const float* __restrict__ csP, const float* __restrict__ csM,
                           float* __restrict__ offP, float* __restrict__ offM) {
  int d = blockIdx.x * 128 + threadIdx.x;
  float rm = 0.f;
  for (int cb = 0; cb < 128; cb += 16) {
    float vals[16];
    #pragma unroll
    for (int u = 0; u < 16; u++) vals[u] = csM[(size_t)(cb + u) * D + d];
    #pragma unroll
    for (int u = 0; u < 16; u++) { offM[(size_t)(cb + u) * D + d] = rm; rm += vals[u]; }
  }
  float rp = 0.f;
  for (int cb = 127; cb >= 15; cb -= 16) {
    float vals[16];
    #pragma unroll
    for (int u = 0; u < 16; u++) vals[u] = csP[(size_t)(cb - u) * D + d];
    #pragma unroll
    for (int u = 0; u < 16; u++) { offP[(size_t)(cb - u) * D + d] = rp; rp += vals[u]; }
  }
}

// ------------- write full prefix (Pre) and suffix (Suf) arrays --------------
template <int D>
__global__ void k_scanwrite(const float* __restrict__ h, const int* __restrict__ sidx,
                            const float* __restrict__ svals,
                            const float* __restrict__ offP, const float* __restrict__ offM,
                            float* __restrict__ Pre, float* __restrict__ Suf) {
  constexpr int CPT = D / 256;
  int c = blockIdx.x, tid = threadIdx.x;
  __shared__ int lidx[32];
  __shared__ float lwp[32], lwm[32];
  if (tid < 32) {
    int r = c * 32 + tid;
    float d = svals[r] - svals[NN - 1];
    lidx[tid] = sidx[r]; lwp[tid] = expf(d); lwm[tid] = expf(0.01f * d);
  }
  __syncthreads();
  float runM[CPT], runP[CPT];
  #pragma unroll
  for (int q = 0; q < CPT; q++) {
    int d = tid + q * 256;
    runM[q] = offM[(size_t)c * D + d];
    runP[q] = offP[(size_t)c * D + d];
  }
  for (int u = 0; u < 32; u++) {
    const float* hr = h + (size_t)lidx[u] * D;
    float fm = lwm[u];
    #pragma unroll
    for (int q = 0; q < CPT; q++) {
      int d = tid + q * 256;
      Pre[(size_t)(c * 32 + u) * D + d] = runM[q];
      runM[q] += fm * hr[d];
    }
  }
  if (c == 127) {
    #pragma unroll
    for (int q = 0; q < CPT; q++) Pre[(size_t)NN * D + tid + q * 256] = runM[q];
    #pragma unroll
    for (int q = 0; q < CPT; q++) Suf[(size_t)NN * D + tid + q * 256] = 0.f;
  }
  for (int u = 31; u >= 0; u--) {
    const float* hr = h + (size_t)lidx[u] * D;
    float fp = lwp[u];
    #pragma unroll
    for (int q = 0; q < CPT; q++) {
      int d = tid + q * 256;
      runP[q] += fp * hr[d];
      Suf[(size_t)(c * 32 + u) * D + d] = runP[q];
    }
  }
}

// ------------- apply (threshold/A/B computed inline) ------------------------
template <int D>
__global__ void k_apply(const float* __restrict__ Pre, const float* __restrict__ Suf,
                        const float* __restrict__ preden, const float* __restrict__ sufden,
                        const float* __restrict__ s1, const float* __restrict__ svals,
                        const float* __restrict__ abp, float* __restrict__ outg) {
  int i = blockIdx.x;
  float ab = abp[0], M2 = svals[NN - 1];
  float alpha = s1[i] + ab;
  float cthr = -alpha;
  int lo = 0, hi = NN;
  while (lo < hi) {
    int mid = (lo + hi) >> 1;
    if (svals[mid] < cthr) lo = mid + 1; else hi = mid;
  }
  int t = lo;
  float e1 = alpha + M2;
  float gam = fmaxf(e1, 0.01f * e1);
  float A = expf(e1 - gam);
  float Bv = expf(0.01f * e1 - gam);
  float den = A * sufden[t] + Bv * preden[t];
  float inv = 1.f / den;
  const float* Pr = Pre + (size_t)t * D;
  const float* Sr = Suf + (size_t)t * D;
  for (int d = threadIdx.x; d < D; d += 256)
    outg[(size_t)i * D + d] = (A * Sr[d] + Bv * Pr[d]) * inv;
}

// ------------- mean-pool over S (2-stage) + final Linear(256,2) -------------
__global__ void k_pool(const float* __restrict__ g2, float* __restrict__ pp) {
  int b = blockIdx.x >> 4, ch = blockIdx.x & 15;
  const float* base = g2 + ((size_t)(b * 1024) + ch * 64) * 256 + threadIdx.x;
  float s = 0.f;
  for (int r = 0; r < 64; r++) s += base[(size_t)r * 256];
  pp[(size_t)blockIdx.x * 256 + threadIdx.x] = s;
}

__global__ void k_head2(const float* __restrict__ pp, const float* __restrict__ fcw,
                        const float* __restrict__ fcb, float* __restrict__ out) {
  __shared__ float pooled[4][256];
  int tid = threadIdx.x;
  for (int b = 0; b < 4; b++) {
    float s = 0.f;
    for (int ch = 0; ch < 16; ch++) s += pp[(size_t)(b * 16 + ch) * 256 + tid];
    pooled[b][tid] = s * (1.f / 1024.f);
  }
  __syncthreads();
  if (tid < 8) {
    int b = tid >> 1, c = tid & 1;
    float acc = fcb[c];
    for (int cc = 0; cc < 256; cc++) acc += pooled[b][cc] * fcw[c * 256 + cc];
    out[b * 2 + c] = acc;
  }
}

// ---------------------------------------------------------------------------
extern "C" void kernel_launch(void* const* d_in, const int* in_sizes, int n_in,
                              void* d_out, int out_size, void* d_ws, size_t ws_size,
                              hipStream_t stream) {
  const float* x    = (const float*)d_in[0];
  const float* ctw  = (const float*)d_in[1];
  const float* ctb  = (const float*)d_in[2];
  const float* bn0g = (const float*)d_in[3];
  const float* bn0b = (const float*)d_in[4];
  const float* bn0m = (const float*)d_in[5];
  const float* bn0v = (const float*)d_in[6];
  const float* c1w  = (const float*)d_in[7];
  const float* c1b  = (const float*)d_in[8];
  const float* bn1g = (const float*)d_in[9];
  const float* bn1b = (const float*)d_in[10];
  const float* bn1m = (const float*)d_in[11];
  const float* bn1v = (const float*)d_in[12];
  const float* c2w  = (const float*)d_in[13];
  const float* c2b  = (const float*)d_in[14];
  const float* bn2g = (const float*)d_in[15];
  const float* bn2b = (const float*)d_in[16];
  const float* bn2m = (const float*)d_in[17];
  const float* bn2v = (const float*)d_in[18];
  const float* g1w  = (const float*)d_in[19];
  const float* g1b  = (const float*)d_in[20];
  const float* g1aw = (const float*)d_in[21];
  const float* g1ab = (const float*)d_in[22];
  const float* g2w  = (const float*)d_in[23];
  const float* g2b  = (const float*)d_in[24];
  const float* g2aw = (const float*)d_in[25];
  const float* g2ab = (const float*)d_in[26];
  const float* fcw  = (const float*)d_in[27];
  const float* fcb  = (const float*)d_in[28];
  float* ws = (float*)d_ws;

  const size_t S0SZ = (size_t)4 * 128 * 4104;   // padded conv_time out
  const size_t S1SZ = (size_t)4 * 256 * 2056;   // padded conv1 out
  const size_t SLOT = (size_t)(NN + 1) * 512;
  float* slot0 = ws;                      // conv_time out -> Suf
  float* slot1 = ws + S0SZ;               // conv1 out -> Pre
  float* slot2 = slot1 + S1SZ;            // conv2 out -> g1 -> g2
  float* slot3 = slot2 + SLOT;            // h1 -> h2
  float* sm    = slot3 + SLOT;            // smalls
  float* s1    = sm;                      // 4096
  float* s2    = sm + 4096;
  float* svals = sm + 8192;
  int*   sidx  = (int*)(sm + 12288);
  float* preden = sm + 16384;             // 4097
  float* sufden = sm + 20488;             // 4097
  float* csP   = sm + 24592;              // 128*512
  float* csM   = csP + 65536;
  float* offP  = csM + 65536;
  float* offM  = offP + 65536;
  int*   rnk   = (int*)(offM + 65536);    // 4096
  float* pp    = offM + 65536 + 4096;     // 16384

  // ---- convs ----
  k_conv_time3<<<BB * 128 * 1024 / 256, 256, 0, stream>>>(x, ctw, ctb, bn0g, bn0b, bn0m, bn0v, slot0);
  k_conv_pair<128, 4096, 4><<<BB * 64 * 16, 128, 0, stream>>>(
      slot0, c1w, c1b, bn1g, bn1b, bn1m, bn1v, slot1, 256);
  k_conv_pair<256, 2048, 0><<<BB * 128 * 8, 128, 0, stream>>>(
      slot1, c2w, c2b, bn2g, bn2b, bn2m, bn2v, slot2, 512);

  // ---- GAT1 ----
  k_gemm_chw<<<dim3(32, 8), 512, 0, stream>>>(slot2, g1w, g1b, slot3);
  k_rowdot<512><<<NN / 4, 256, 0, stream>>>(slot3, g1aw, s1, s2, rnk);
  k_rank<<<dim3(16, 4), 256, 0, stream>>>(s2, rnk);
  k_scatter<<<16, 256, 0, stream>>>(s2, rnk, svals, sidx);
  k_scan_den<<<1, 256, 0, stream>>>(svals, preden, sufden);
  k_chunksum<512><<<128, 256, 0, stream>>>(slot3, sidx, svals, csP, csM);
  k_chunkoff<512><<<4, 128, 0, stream>>>(csP, csM, offP, offM);
  k_scanwrite<512><<<128, 256, 0, stream>>>(slot3, sidx, svals, offP, offM, slot1, slot0);
  k_apply<512><<<NN, 256, 0, stream>>>(slot1, slot0, preden, sufden, s1, svals, g1ab, slot2);

  // ---- GAT2 ----
  k_gemm_rm<<<dim3(64, 4), 256, 0, stream>>>(slot2, g2w, g2b, slot3);
  k_rowdot<256><<<NN / 4, 256, 0, stream>>>(slot3, g2aw, s1, s2, rnk);
  k_rank<<<dim3(16, 4), 256, 0, stream>>>(s2, rnk);
  k_scatter<<<16, 256, 0, stream>>>(s2, rnk, svals, sidx);
  k_scan_den<<<1, 256, 0, stream>>>(svals, preden, sufden);
  k_chunksum<256><<<128, 256, 0, stream>>>(slot3, sidx, svals, csP, csM);
  k_chunkoff<256><<<2, 128, 0, stream>>>(csP, csM, offP, offM);
  k_scanwrite<256><<<128, 256, 0, stream>>>(slot3, sidx, svals, offP, offM, slot1, slot0);
  k_apply<256><<<NN, 256, 0, stream>>>(slot1, slot0, preden, sufden, s1, svals, g2ab, slot2);

  // ---- head ----
  k_pool<<<BB * 16, 256, 0, stream>>>(slot2, pp);
  k_head2<<<1, 256, 0, stream>>>(pp, fcw, fcb, (float*)d_out);
}